// Round 1
// baseline (4821.182 us; speedup 1.0000x reference)
//
#include <hip/hip_runtime.h>
#include <stdint.h>
#include <math.h>

// Problem constants
#define IMGN 448
#define HW   200704          // 448*448
#define NBATCH 64
#define SROW 196608          // 256*768 elements per batch in x/h/y
#define STOT 12582912        // 64*256*768
#define NBINS 36

// ---------------- threefry2x32 (JAX-compatible, 20 rounds) ----------------
__host__ __device__ __forceinline__ uint32_t rotl32(uint32_t v, int r) {
  return (v << r) | (v >> (32 - r));
}

__host__ __device__ __forceinline__ void tf2x32(uint32_t k0, uint32_t k1,
                                                uint32_t x0, uint32_t x1,
                                                uint32_t &o0, uint32_t &o1) {
  uint32_t k2 = k0 ^ k1 ^ 0x1BD11BDAu;
  uint32_t v0 = x0 + k0, v1 = x1 + k1;
#define TFR(r) { v0 += v1; v1 = rotl32(v1, r); v1 ^= v0; }
  TFR(13) TFR(15) TFR(26) TFR(6)   v0 += k1; v1 += k2 + 1u;
  TFR(17) TFR(29) TFR(16) TFR(24)  v0 += k2; v1 += k0 + 2u;
  TFR(13) TFR(15) TFR(26) TFR(6)   v0 += k0; v1 += k1 + 3u;
  TFR(17) TFR(29) TFR(16) TFR(24)  v0 += k1; v1 += k2 + 4u;
  TFR(13) TFR(15) TFR(26) TFR(6)   v0 += k2; v1 += k0 + 5u;
#undef TFR
  o0 = v0; o1 = v1;
}

// partitionable-mode random bits -> uniform float in [0,1)
__device__ __forceinline__ float tf_uniform(uint32_t k0, uint32_t k1, uint32_t idx) {
  uint32_t a, b;
  tf2x32(k0, k1, 0u, idx, a, b);
  uint32_t bits = a ^ b;
  return __uint_as_float((bits >> 9) | 0x3F800000u) - 1.0f;
}

// ---------------- APE pipeline ----------------

// win table (fp64) + zero the bins
__global__ void k_prep(double *win, double *bins) {
  int t = threadIdx.x;
  if (t < IMGN) {
    double ang = 6.283185307179586476925286766559 * (double)t / (double)IMGN;
    win[t] = 0.5 - 0.5 * cos(ang);
  }
  for (int i = t; i < NBATCH * NBINS; i += blockDim.x) bins[i] = 0.0;
}

// grayscale (exact fp32 reference formula) + per-block fp64 partial sums
__global__ __launch_bounds__(256) void k_gray(const float *__restrict__ img,
                                              float *__restrict__ gray,
                                              double *__restrict__ part) {
  int b = blockIdx.y;
  int pix = blockIdx.x * 256 + threadIdx.x;   // 784*256 == 200704 exactly
  const float *p = img + (size_t)b * 3 * HW;
  float v0 = p[pix], v1 = p[HW + pix], v2 = p[2 * HW + pix];
  float t0 = (v0 * 0.229f + 0.485f) * 0.2989f;
  float t1 = (v1 * 0.224f + 0.456f) * 0.587f;
  float t2 = (v2 * 0.225f + 0.406f) * 0.114f;
  float g = (t0 + t1) + t2;
  gray[(size_t)b * HW + pix] = g;

  __shared__ double sd[256];
  sd[threadIdx.x] = (double)g;
  __syncthreads();
  for (int s = 128; s > 0; s >>= 1) {
    if (threadIdx.x < s) sd[threadIdx.x] += sd[threadIdx.x + s];
    __syncthreads();
  }
  if (threadIdx.x == 0) part[b * 784 + blockIdx.x] = sd[0];
}

__global__ __launch_bounds__(256) void k_mean(const double *__restrict__ part,
                                              double *__restrict__ mean) {
  int b = blockIdx.x;
  __shared__ double sd[256];
  double s = 0.0;
  for (int i = threadIdx.x; i < 784; i += 256) s += part[b * 784 + i];
  sd[threadIdx.x] = s;
  __syncthreads();
  for (int st = 128; st > 0; st >>= 1) {
    if (threadIdx.x < st) sd[threadIdx.x] += sd[threadIdx.x + st];
    __syncthreads();
  }
  if (threadIdx.x == 0) mean[b] = sd[0] / (double)HW;
}

// Pass 1: row DFT.  c1[b][v][y] = sum_x (g-m)*win_y*win_x * e^{-2pi i v x/448},  v in [0,224]
__global__ __launch_bounds__(256) void k_dft_rows(const float *__restrict__ gray,
                                                  const double *__restrict__ win,
                                                  const double *__restrict__ mean,
                                                  float *__restrict__ c1) {
  __shared__ double t[IMGN];
  __shared__ double twc[IMGN], tws[IMGN];
  int b = blockIdx.y, y = blockIdx.x, tid = threadIdx.x;
  double m = mean[b], wy = win[y];
  for (int x = tid; x < IMGN; x += 256)
    t[x] = ((double)gray[(size_t)b * HW + y * IMGN + x] - m) * wy * win[x];
  for (int k = tid; k < IMGN; k += 256) {
    double ang = -6.283185307179586476925286766559 * (double)k / (double)IMGN;
    twc[k] = cos(ang);
    tws[k] = sin(ang);
  }
  __syncthreads();
  int v = tid;
  if (v <= 224) {
    double ar = 0.0, ai = 0.0;
    int idx = 0;
    for (int x = 0; x < IMGN; ++x) {
      double tv = t[x];
      ar += tv * twc[idx];
      ai += tv * tws[idx];
      idx += v; if (idx >= IMGN) idx -= IMGN;
    }
    size_t o = ((size_t)b * 225 + v) * IMGN + y;
    c1[2 * o]     = (float)ar;
    c1[2 * o + 1] = (float)ai;
  }
}

// fftshift + radial mask + angular bin for unshifted freq (u,v); fp64 exact-margin tests
__device__ __forceinline__ void addbin(double *lb, int u, int v, double P) {
  double yy = (double)((u + 224) % IMGN) - 223.5;
  double xx = (double)((v + 224) % IMGN) - 223.5;
  double r2 = xx * xx + yy * yy;                  // exact in fp64
  // (0.05*rmax)^2 = 249.76125 ; (0.95*rmax)^2 = 90163.81125  (rmax^2 = 2*223.5^2)
  if (r2 < 249.76125 || r2 > 90163.81125) return;
  double th = atan2(yy, xx);
  if (th < 0.0) th += 6.283185307179586476925286766559;
  int i = (int)(th / 0.17453292519943295769236907684886);  // 2*pi/36
  if (i > 35) i = 35;
  if (i < 0) i = 0;
  atomicAdd(&lb[i], P);
}

// Pass 2: column DFT + power + angular-bin accumulation (with conjugate-mirror columns)
__global__ __launch_bounds__(256) void k_dft_cols(const float *__restrict__ c1,
                                                  double *__restrict__ bins) {
  __shared__ double cr[IMGN], ci[IMGN];
  __shared__ double twc[IMGN], tws[IMGN];
  __shared__ double lb[NBINS];
  int b = blockIdx.y, v = blockIdx.x, tid = threadIdx.x;
  for (int i = tid; i < NBINS; i += 256) lb[i] = 0.0;
  size_t base = ((size_t)b * 225 + v) * IMGN;
  for (int y = tid; y < IMGN; y += 256) {
    cr[y] = (double)c1[2 * (base + y)];
    ci[y] = (double)c1[2 * (base + y) + 1];
  }
  for (int k = tid; k < IMGN; k += 256) {
    double ang = -6.283185307179586476925286766559 * (double)k / (double)IMGN;
    twc[k] = cos(ang);
    tws[k] = sin(ang);
  }
  __syncthreads();
  for (int u = tid; u < IMGN; u += 256) {
    double fr = 0.0, fi = 0.0;
    int idx = 0;
    for (int y = 0; y < IMGN; ++y) {
      double c = twc[idx], s = tws[idx];
      double xr = cr[y], xi = ci[y];
      fr += c * xr - s * xi;
      fi += c * xi + s * xr;
      idx += u; if (idx >= IMGN) idx -= IMGN;
    }
    double P = fr * fr + fi * fi;
    addbin(lb, u, v, P);
    if (v >= 1 && v <= 223) addbin(lb, (IMGN - u) % IMGN, IMGN - v, P);
  }
  __syncthreads();
  for (int i = tid; i < NBINS; i += 256)
    if (lb[i] != 0.0) atomicAdd(&bins[b * NBINS + i], lb[i]);
}

// entropy -> ape -> drop prob -> fp32 threshold & scale
__global__ void k_probs(const double *__restrict__ bins, float *__restrict__ ts) {
  int b = threadIdx.x;
  if (b >= NBATCH) return;
  double T = 0.0;
  for (int i = 0; i < NBINS; ++i) T += bins[b * NBINS + i];
  double H = 0.0;
  for (int i = 0; i < NBINS; ++i) {
    double p = bins[b * NBINS + i] / (T + 1e-12);
    H -= p * log(p + 1e-12);
  }
  double ape = H / 3.5835189384561099;   // log(36)
  if (ape > 1.0) ape = 1.0;
  if (ape < 0.0) ape = 0.0;
  if (T <= 1e-12) ape = 0.0;
  double adj = tanh((0.78 - ape) * 4.0);
  double drop = (adj >= 0.0) ? (0.3 + adj * 0.3) : (0.3 + adj * 0.2);
  if (drop < 0.1) drop = 0.1;
  if (drop > 0.6) drop = 0.6;
  float p32 = (float)drop;
  ts[b]          = 1.0f - p32;                      // bernoulli threshold (keep if u < t)
  ts[NBATCH + b] = 1.0f / (1.0f - p32 + 1e-8f);     // keep scale
}

// ---------------- dropout + MLP ----------------

__global__ __launch_bounds__(256) void k_drop(const float *__restrict__ x,
                                              float *__restrict__ out,
                                              const float *__restrict__ ts,
                                              uint32_t k0, uint32_t k1) {
  int i = blockIdx.x * 256 + threadIdx.x;   // 49152*256 == STOT exactly
  int b = i / SROW;
  float u = tf_uniform(k0, k1, (uint32_t)i);
  float t = ts[b], s = ts[NBATCH + b];
  out[i] = (u < t) ? x[i] * s : 0.0f;
}

// C[M=16384 x 768] = A[M x 768] * B^T (B row-major 768x768, row = output col)
// MODE 1: gelu(exact) then dropout ; MODE 2: dropout only
template <int MODE>
__global__ __launch_bounds__(256) void k_gemm(const float *__restrict__ A,
                                              const float *__restrict__ Bw,
                                              float *__restrict__ out,
                                              const float *__restrict__ ts,
                                              uint32_t k0, uint32_t k1) {
  __shared__ float As[16][65];
  __shared__ float Bs[16][65];
  int bm = blockIdx.x * 64, bn = blockIdx.y * 64;
  int tid = threadIdx.x;
  int tx = tid & 15, ty = tid >> 4;
  float acc[4][4] = {};
  for (int kb = 0; kb < 768; kb += 16) {
#pragma unroll
    for (int i = 0; i < 4; ++i) {
      int e = tid + i * 256;
      int r = e >> 4, k = e & 15;
      As[k][r] = A[(size_t)(bm + r) * 768 + kb + k];
      Bs[k][r] = Bw[(size_t)(bn + r) * 768 + kb + k];
    }
    __syncthreads();
#pragma unroll
    for (int k = 0; k < 16; ++k) {
      float a[4], bv[4];
#pragma unroll
      for (int i = 0; i < 4; ++i) a[i] = As[k][ty * 4 + i];
#pragma unroll
      for (int j = 0; j < 4; ++j) bv[j] = Bs[k][tx * 4 + j];
#pragma unroll
      for (int i = 0; i < 4; ++i)
#pragma unroll
        for (int j = 0; j < 4; ++j) acc[i][j] += a[i] * bv[j];
    }
    __syncthreads();
  }
#pragma unroll
  for (int i = 0; i < 4; ++i) {
    int m = bm + ty * 4 + i;
    int bidx = m >> 8;                       // 256 rows per batch
    float t = ts[bidx], s = ts[NBATCH + bidx];
#pragma unroll
    for (int j = 0; j < 4; ++j) {
      int c = bn + tx * 4 + j;
      float val = acc[i][j];
      if (MODE == 1)
        val = 0.5f * val * (1.0f + erff(val * 0.70710678118654752440f));
      uint32_t idx = (uint32_t)m * 768u + (uint32_t)c;
      float u = tf_uniform(k0, k1, idx);
      out[(size_t)m * 768 + c] = (u < t) ? val * s : 0.0f;
    }
  }
}

// ---------------- launch ----------------
extern "C" void kernel_launch(void *const *d_in, const int *in_sizes, int n_in,
                              void *d_out, int out_size, void *d_ws, size_t ws_size,
                              hipStream_t stream) {
  (void)in_sizes; (void)n_in; (void)out_size; (void)ws_size;
  const float *images = (const float *)d_in[0];
  const float *x  = (const float *)d_in[1];
  const float *w1 = (const float *)d_in[2];
  const float *w2 = (const float *)d_in[3];

  char *ws = (char *)d_ws;
  double *win  = (double *)(ws + 0);          // 448 doubles
  double *mean = (double *)(ws + 4096);       // 64 doubles
  double *bins = (double *)(ws + 8192);       // 64*36 doubles
  float  *ts   = (float *) (ws + 32768);      // t[64] + s[64]
  double *part = (double *)(ws + 65536);      // 784*64 doubles
  float  *gray = (float *) (ws + 524288);     // 64*200704 floats (51.4 MB)
  float  *c1   = (float *) (ws + 51904512ull);// 64*225*448 complex fp32 (51.6 MB)
  float  *xd   = gray;                        // reuse after APE done
  float  *hd   = c1;                          // reuse after APE done
  float  *yout = (float *)d_out;

  // fold-like split of key(1) = (0,1): key_i = threefry((0,1),(0,i))
  uint32_t keys[6];
  tf2x32(0u, 1u, 0u, 0u, keys[0], keys[1]);
  tf2x32(0u, 1u, 0u, 1u, keys[2], keys[3]);
  tf2x32(0u, 1u, 0u, 2u, keys[4], keys[5]);

  k_prep<<<1, 512, 0, stream>>>(win, bins);
  k_gray<<<dim3(784, 64), 256, 0, stream>>>(images, gray, part);
  k_mean<<<64, 256, 0, stream>>>(part, mean);
  k_dft_rows<<<dim3(448, 64), 256, 0, stream>>>(gray, win, mean, c1);
  k_dft_cols<<<dim3(225, 64), 256, 0, stream>>>(c1, bins);
  k_probs<<<1, 64, 0, stream>>>(bins, ts);
  k_drop<<<49152, 256, 0, stream>>>(x, xd, ts, keys[0], keys[1]);
  k_gemm<1><<<dim3(256, 12), 256, 0, stream>>>(xd, w1, hd, ts, keys[2], keys[3]);
  k_gemm<2><<<dim3(256, 12), 256, 0, stream>>>(hd, w2, yout, ts, keys[4], keys[5]);
}

// Round 2
// 2059.093 us; speedup vs baseline: 2.3414x; 2.3414x over previous
//
#include <hip/hip_runtime.h>
#include <stdint.h>
#include <math.h>

// Problem constants
#define IMGN 448
#define HW   200704          // 448*448
#define NBATCH 64
#define SROW 196608          // 256*768 elements per batch in x/h/y
#define NBINS 36

// workspace offsets (bytes)
#define WS_WIN  0            // 448 fp32
#define WS_BINS 4096         // 64*36 double
#define WS_TS   22528        // 128 fp32
#define WS_TWC  32768        // 448*448 fp32 cos
#define WS_TWS  835584       // 448*448 fp32 sin
#define WS_BIDX 1638400      // 448*448 u8 bin index (255 = masked)
#define WS_C1R  2097152      // 64*225*448 fp32
#define WS_C1I  27901952     // 64*225*448 fp32
#define WS_HD   2097152      // reuse c1 region after cols pass

// ---------------- threefry2x32 (JAX-compatible, 20 rounds) ----------------
__host__ __device__ __forceinline__ uint32_t rotl32(uint32_t v, int r) {
  return (v << r) | (v >> (32 - r));
}

__host__ __device__ __forceinline__ void tf2x32(uint32_t k0, uint32_t k1,
                                                uint32_t x0, uint32_t x1,
                                                uint32_t &o0, uint32_t &o1) {
  uint32_t k2 = k0 ^ k1 ^ 0x1BD11BDAu;
  uint32_t v0 = x0 + k0, v1 = x1 + k1;
#define TFR(r) { v0 += v1; v1 = rotl32(v1, r); v1 ^= v0; }
  TFR(13) TFR(15) TFR(26) TFR(6)   v0 += k1; v1 += k2 + 1u;
  TFR(17) TFR(29) TFR(16) TFR(24)  v0 += k2; v1 += k0 + 2u;
  TFR(13) TFR(15) TFR(26) TFR(6)   v0 += k0; v1 += k1 + 3u;
  TFR(17) TFR(29) TFR(16) TFR(24)  v0 += k1; v1 += k2 + 4u;
  TFR(13) TFR(15) TFR(26) TFR(6)   v0 += k2; v1 += k0 + 5u;
#undef TFR
  o0 = v0; o1 = v1;
}

__device__ __forceinline__ float tf_uniform(uint32_t k0, uint32_t k1, uint32_t idx) {
  uint32_t a, b;
  tf2x32(k0, k1, 0u, idx, a, b);
  uint32_t bits = a ^ b;
  return __uint_as_float((bits >> 9) | 0x3F800000u) - 1.0f;
}

// ---------------- prep: twiddle table, bin-index table, window, zero bins --
__global__ __launch_bounds__(256) void k_prep(float *__restrict__ win,
                                              double *__restrict__ bins,
                                              float *__restrict__ twc,
                                              float *__restrict__ tws,
                                              uint8_t *__restrict__ bidx) {
  int t = blockIdx.x * 256 + threadIdx.x;   // 784*256 == 200704 exactly
  int a = t / IMGN, b = t % IMGN;
  int m = (a * b) % IMGN;
  double ang = -6.283185307179586476925286766559 * (double)m / 448.0;
  twc[t] = (float)cos(ang);
  tws[t] = (float)sin(ang);
  // exact fp64 mask/bin test, identical constants to the verified R1 kernel
  double yy = (double)((a + 224) % IMGN) - 223.5;
  double xx = (double)((b + 224) % IMGN) - 223.5;
  double r2 = xx * xx + yy * yy;
  uint8_t idx = 255;
  if (r2 >= 249.76125 && r2 <= 90163.81125) {
    double th = atan2(yy, xx);
    if (th < 0.0) th += 6.283185307179586476925286766559;
    int i = (int)(th / 0.17453292519943295769236907684886);
    if (i > 35) i = 35;
    if (i < 0) i = 0;
    idx = (uint8_t)i;
  }
  bidx[t] = idx;
  if (t < IMGN) {
    double ang2 = 6.283185307179586476925286766559 * (double)t / 448.0;
    win[t] = (float)(0.5 - 0.5 * cos(ang2));
  }
  if (t < NBATCH * NBINS) bins[t] = 0.0;
}

// ---------------- Pass 1: row DFT as tiled GEMM -----------------
// C1[b][v][y] = sum_x (gray[b,y,x]*win_y*win_x) * cis(-2pi v x/448), v in [0,225)
// (mean subtraction dropped: its exact spectrum lives at the 9 DC-adjacent
//  points, all inside the r<0.05*rmax mask -> provably no effect on bins)
__global__ __launch_bounds__(256) void k_rows(const float *__restrict__ img,
                                              const float *__restrict__ win,
                                              const float *__restrict__ twc,
                                              const float *__restrict__ tws,
                                              float *__restrict__ c1r,
                                              float *__restrict__ c1i) {
  __shared__ float As[32][65];   // [x][y] windowed gray tile
  __shared__ float Bc[32][65];   // [x][v] twiddle cos
  __shared__ float Bs[32][65];   // [x][v] twiddle sin
  int b = blockIdx.z, y0 = blockIdx.x * 64, v0 = blockIdx.y * 64;
  int t = threadIdx.x;
  int tx = t & 15, ty = t >> 4;            // tx -> v group, ty -> y group
  const float *ib = img + (size_t)b * 3 * HW;
  float ar[4][4] = {}, ai[4][4] = {};
  for (int x0 = 0; x0 < IMGN; x0 += 32) {
#pragma unroll
    for (int i = 0; i < 8; ++i) {          // stage 64y x 32x gray tile
      int l = t + 256 * i;
      int xx = l & 31, yy = l >> 5;
      int g = (y0 + yy) * IMGN + x0 + xx;
      float r = ib[g], gg = ib[HW + g], bl = ib[2 * HW + g];
      float t0 = (r * 0.229f + 0.485f) * 0.2989f;
      float t1 = (gg * 0.224f + 0.456f) * 0.587f;
      float t2 = (bl * 0.225f + 0.406f) * 0.114f;
      As[xx][yy] = ((t0 + t1) + t2) * win[y0 + yy] * win[x0 + xx];
    }
#pragma unroll
    for (int i = 0; i < 8; ++i) {          // stage 32x x 64v twiddle tile
      int l = t + 256 * i;
      int vv = l & 63, xk = l >> 6;
      int ti = (x0 + xk) * IMGN + v0 + vv;
      Bc[xk][vv] = twc[ti];
      Bs[xk][vv] = tws[ti];
    }
    __syncthreads();
#pragma unroll
    for (int xk = 0; xk < 32; ++xk) {
      float av[4], cv[4], sv[4];
#pragma unroll
      for (int i = 0; i < 4; ++i) av[i] = As[xk][ty * 4 + i];
#pragma unroll
      for (int j = 0; j < 4; ++j) { cv[j] = Bc[xk][tx * 4 + j]; sv[j] = Bs[xk][tx * 4 + j]; }
#pragma unroll
      for (int i = 0; i < 4; ++i)
#pragma unroll
        for (int j = 0; j < 4; ++j) {
          ar[i][j] += av[i] * cv[j];
          ai[i][j] += av[i] * sv[j];
        }
    }
    __syncthreads();
  }
#pragma unroll
  for (int j = 0; j < 4; ++j) {
    int v = v0 + tx * 4 + j;
    if (v < 225) {
      size_t base = ((size_t)b * 225 + v) * IMGN + y0 + ty * 4;
#pragma unroll
      for (int i = 0; i < 4; ++i) { c1r[base + i] = ar[i][j]; c1i[base + i] = ai[i][j]; }
    }
  }
}

// ---------------- Pass 2: column DFT as tiled GEMM + power + binning ------
// F[u][v] = sum_y cis(-2pi u y/448) * C1[v][y]; P=|F|^2 binned via bidx table.
__global__ __launch_bounds__(256) void k_cols(const float *__restrict__ c1r,
                                              const float *__restrict__ c1i,
                                              const float *__restrict__ twc,
                                              const float *__restrict__ tws,
                                              const uint8_t *__restrict__ bidx,
                                              double *__restrict__ bins) {
  __shared__ float Ar[32][65], Ai[32][65];  // [y][v] C1 tile
  __shared__ float Bc[32][65], Bs[32][65];  // [y][u] twiddle tile
  __shared__ double lb[NBINS];
  int b = blockIdx.z, u0 = blockIdx.x * 64, v0 = blockIdx.y * 64;
  int t = threadIdx.x;
  int tx = t & 15, ty = t >> 4;            // tx -> v group, ty -> u group
  if (t < NBINS) lb[t] = 0.0;
  float fr[4][4] = {}, fi[4][4] = {};
  for (int y0 = 0; y0 < IMGN; y0 += 32) {
#pragma unroll
    for (int i = 0; i < 8; ++i) {          // stage C1 tile
      int l = t + 256 * i;
      int yk = l & 31, vv = l >> 5;
      int v = v0 + vv;
      float vr = 0.f, vi = 0.f;
      if (v < 225) {
        size_t o = ((size_t)b * 225 + v) * IMGN + y0 + yk;
        vr = c1r[o]; vi = c1i[o];
      }
      Ar[yk][vv] = vr; Ai[yk][vv] = vi;
    }
#pragma unroll
    for (int i = 0; i < 8; ++i) {          // stage twiddle tile
      int l = t + 256 * i;
      int uu = l & 63, yk = l >> 6;
      int ti = (y0 + yk) * IMGN + u0 + uu;
      Bc[yk][uu] = twc[ti]; Bs[yk][uu] = tws[ti];
    }
    __syncthreads();
#pragma unroll
    for (int yk = 0; yk < 32; ++yk) {
      float xr[4], xi[4], cv[4], sv[4];
#pragma unroll
      for (int j = 0; j < 4; ++j) { xr[j] = Ar[yk][tx * 4 + j]; xi[j] = Ai[yk][tx * 4 + j]; }
#pragma unroll
      for (int i = 0; i < 4; ++i) { cv[i] = Bc[yk][ty * 4 + i]; sv[i] = Bs[yk][ty * 4 + i]; }
#pragma unroll
      for (int i = 0; i < 4; ++i)
#pragma unroll
        for (int j = 0; j < 4; ++j) {
          fr[i][j] += cv[i] * xr[j] - sv[i] * xi[j];
          fi[i][j] += cv[i] * xi[j] + sv[i] * xr[j];
        }
    }
    __syncthreads();
  }
  // power + angular binning (mirror covers v in [225,448))
#pragma unroll
  for (int i = 0; i < 4; ++i) {
    int u = u0 + ty * 4 + i;
#pragma unroll
    for (int j = 0; j < 4; ++j) {
      int v = v0 + tx * 4 + j;
      if (v >= 225) continue;
      double P = (double)fr[i][j] * (double)fr[i][j] + (double)fi[i][j] * (double)fi[i][j];
      int i1 = bidx[u * IMGN + v];
      if (i1 < 36) atomicAdd(&lb[i1], P);
      if (v >= 1 && v <= 223) {
        int um = (448 - u) % 448;
        int vm = 448 - v;
        int i2 = bidx[um * IMGN + vm];
        if (i2 < 36) atomicAdd(&lb[i2], P);
      }
    }
  }
  __syncthreads();
  if (t < NBINS && lb[t] != 0.0) atomicAdd(&bins[b * NBINS + t], lb[t]);
}

// ---------------- entropy -> ape -> drop prob -> fp32 threshold & scale ---
__global__ void k_probs(const double *__restrict__ bins, float *__restrict__ ts) {
  int b = threadIdx.x;
  if (b >= NBATCH) return;
  double T = 0.0;
  for (int i = 0; i < NBINS; ++i) T += bins[b * NBINS + i];
  double H = 0.0;
  for (int i = 0; i < NBINS; ++i) {
    double p = bins[b * NBINS + i] / (T + 1e-12);
    H -= p * log(p + 1e-12);
  }
  double ape = H / 3.5835189384561099;   // log(36)
  if (ape > 1.0) ape = 1.0;
  if (ape < 0.0) ape = 0.0;
  if (T <= 1e-12) ape = 0.0;
  double adj = tanh((0.78 - ape) * 4.0);
  double drop = (adj >= 0.0) ? (0.3 + adj * 0.3) : (0.3 + adj * 0.2);
  if (drop < 0.1) drop = 0.1;
  if (drop > 0.6) drop = 0.6;
  float p32 = (float)drop;
  ts[b]          = 1.0f - p32;
  ts[NBATCH + b] = 1.0f / (1.0f - p32 + 1e-8f);
}

// ---------------- dropout + MLP ----------------
__global__ __launch_bounds__(256) void k_drop(const float *__restrict__ x,
                                              float *__restrict__ out,
                                              const float *__restrict__ ts,
                                              uint32_t k0, uint32_t k1) {
  int i = blockIdx.x * 256 + threadIdx.x;   // 49152*256 == 12582912 exactly
  int b = i / SROW;
  float u = tf_uniform(k0, k1, (uint32_t)i);
  float t = ts[b], s = ts[NBATCH + b];
  out[i] = (u < t) ? x[i] * s : 0.0f;
}

// C[16384 x 768] = A[16384 x 768] * B^T ; MODE 1: gelu+dropout, MODE 2: dropout
template <int MODE>
__global__ __launch_bounds__(256) void k_gemm(const float *__restrict__ A,
                                              const float *__restrict__ Bw,
                                              float *__restrict__ out,
                                              const float *__restrict__ ts,
                                              uint32_t k0, uint32_t k1) {
  __shared__ float As[16][65];
  __shared__ float Bs[16][65];
  int bm = blockIdx.x * 64, bn = blockIdx.y * 64;
  int tid = threadIdx.x;
  int tx = tid & 15, ty = tid >> 4;
  float acc[4][4] = {};
  for (int kb = 0; kb < 768; kb += 16) {
#pragma unroll
    for (int i = 0; i < 4; ++i) {
      int e = tid + i * 256;
      int r = e >> 4, k = e & 15;
      As[k][r] = A[(size_t)(bm + r) * 768 + kb + k];
      Bs[k][r] = Bw[(size_t)(bn + r) * 768 + kb + k];
    }
    __syncthreads();
#pragma unroll
    for (int k = 0; k < 16; ++k) {
      float a[4], bv[4];
#pragma unroll
      for (int i = 0; i < 4; ++i) a[i] = As[k][ty * 4 + i];
#pragma unroll
      for (int j = 0; j < 4; ++j) bv[j] = Bs[k][tx * 4 + j];
#pragma unroll
      for (int i = 0; i < 4; ++i)
#pragma unroll
        for (int j = 0; j < 4; ++j) acc[i][j] += a[i] * bv[j];
    }
    __syncthreads();
  }
#pragma unroll
  for (int i = 0; i < 4; ++i) {
    int m = bm + ty * 4 + i;
    int bidx = m >> 8;                       // 256 rows per batch
    float t = ts[bidx], s = ts[NBATCH + bidx];
#pragma unroll
    for (int j = 0; j < 4; ++j) {
      int c = bn + tx * 4 + j;
      float val = acc[i][j];
      if (MODE == 1)
        val = 0.5f * val * (1.0f + erff(val * 0.70710678118654752440f));
      uint32_t idx = (uint32_t)m * 768u + (uint32_t)c;
      float u = tf_uniform(k0, k1, idx);
      out[(size_t)m * 768 + c] = (u < t) ? val * s : 0.0f;
    }
  }
}

// ---------------- launch ----------------
extern "C" void kernel_launch(void *const *d_in, const int *in_sizes, int n_in,
                              void *d_out, int out_size, void *d_ws, size_t ws_size,
                              hipStream_t stream) {
  (void)in_sizes; (void)n_in; (void)out_size; (void)ws_size;
  const float *images = (const float *)d_in[0];
  const float *x  = (const float *)d_in[1];
  const float *w1 = (const float *)d_in[2];
  const float *w2 = (const float *)d_in[3];

  char *ws = (char *)d_ws;
  float   *win  = (float *)  (ws + WS_WIN);
  double  *bins = (double *) (ws + WS_BINS);
  float   *ts   = (float *)  (ws + WS_TS);
  float   *twc  = (float *)  (ws + WS_TWC);
  float   *tws  = (float *)  (ws + WS_TWS);
  uint8_t *bidx = (uint8_t *)(ws + WS_BIDX);
  float   *c1r  = (float *)  (ws + WS_C1R);
  float   *c1i  = (float *)  (ws + WS_C1I);
  float   *hd   = (float *)  (ws + WS_HD);   // reuses c1 region after cols
  float   *xd   = (float *)d_out;            // dropout(x) staged in d_out
  float   *yout = (float *)d_out;

  uint32_t keys[6];
  tf2x32(0u, 1u, 0u, 0u, keys[0], keys[1]);
  tf2x32(0u, 1u, 0u, 1u, keys[2], keys[3]);
  tf2x32(0u, 1u, 0u, 2u, keys[4], keys[5]);

  k_prep<<<784, 256, 0, stream>>>(win, bins, twc, tws, bidx);
  k_rows<<<dim3(7, 4, 64), 256, 0, stream>>>(images, win, twc, tws, c1r, c1i);
  k_cols<<<dim3(7, 4, 64), 256, 0, stream>>>(c1r, c1i, twc, tws, bidx, bins);
  k_probs<<<1, 64, 0, stream>>>(bins, ts);
  k_drop<<<49152, 256, 0, stream>>>(x, xd, ts, keys[0], keys[1]);
  k_gemm<1><<<dim3(256, 12), 256, 0, stream>>>(xd, w1, hd, ts, keys[2], keys[3]);
  k_gemm<2><<<dim3(256, 12), 256, 0, stream>>>(hd, w2, yout, ts, keys[4], keys[5]);
}

// Round 3
// 767.837 us; speedup vs baseline: 6.2789x; 2.6817x over previous
//
#include <hip/hip_runtime.h>
#include <stdint.h>
#include <math.h>

typedef __attribute__((ext_vector_type(8))) short short8;
typedef __attribute__((ext_vector_type(4))) float floatx4;

#define IMGN 448
#define HW   200704
#define NBATCH 64
#define NBINS 36

// ---------------- workspace map (bytes) ----------------
// smalls
#define WS_WIN   0u           // 448 fp32
#define WS_BINS  4096u        // 64*36 double
#define WS_TS    24576u       // 128 fp32
#define WS_BIDX  32768u       // 200704 u8
// twiddle frag mats: M=448 (MB=28), K=448 (KB=14): 28*14*64*16 = 401408 each
#define WS_TW    1048576u
#define TWSZ     401408u
// W frag mats: N=768 (48), K=768 (24): 48*24*64*16 = 1179648 each
#define WS_W     4194304u
#define WSZ      1179648u
// REG1 @16MB: G frags (2 x 25690112) -> colsB frags (4 x 13762560) -> xd frags (2 x 25165824)
#define WS_REG1  16777216u
#define GSZ      25690112u
#define CBSZ     13762560u
#define XSZ      25165824u
// REG2 @72MB: Cr/Ci fp32 (2 x 29360128) -> h frags (2 x 25165824)
#define WS_REG2  75497472u
#define CRSZ     29360128u

// ---------------- threefry2x32 (JAX partitionable) ----------------
__host__ __device__ __forceinline__ uint32_t rotl32(uint32_t v, int r) {
  return (v << r) | (v >> (32 - r));
}
__host__ __device__ __forceinline__ void tf2x32(uint32_t k0, uint32_t k1,
                                                uint32_t x0, uint32_t x1,
                                                uint32_t &o0, uint32_t &o1) {
  uint32_t k2 = k0 ^ k1 ^ 0x1BD11BDAu;
  uint32_t v0 = x0 + k0, v1 = x1 + k1;
#define TFR(r) { v0 += v1; v1 = rotl32(v1, r); v1 ^= v0; }
  TFR(13) TFR(15) TFR(26) TFR(6)   v0 += k1; v1 += k2 + 1u;
  TFR(17) TFR(29) TFR(16) TFR(24)  v0 += k2; v1 += k0 + 2u;
  TFR(13) TFR(15) TFR(26) TFR(6)   v0 += k0; v1 += k1 + 3u;
  TFR(17) TFR(29) TFR(16) TFR(24)  v0 += k1; v1 += k2 + 4u;
  TFR(13) TFR(15) TFR(26) TFR(6)   v0 += k2; v1 += k0 + 5u;
#undef TFR
  o0 = v0; o1 = v1;
}
__device__ __forceinline__ float tf_uniform(uint32_t k0, uint32_t k1, uint32_t idx) {
  uint32_t a, b;
  tf2x32(k0, k1, 0u, idx, a, b);
  uint32_t bits = a ^ b;
  return __uint_as_float((bits >> 9) | 0x3F800000u) - 1.0f;
}

// ---------------- bf16 split helpers ----------------
__device__ __forceinline__ unsigned short bf16rne(float v) {
  unsigned u = __float_as_uint(v);
  return (unsigned short)((u + 0x7fffu + ((u >> 16) & 1u)) >> 16);
}
__device__ __forceinline__ void split2(float v, unsigned short &h, unsigned short &l) {
  h = bf16rne(v);
  float fh = __uint_as_float(((unsigned)h) << 16);
  l = bf16rne(v - fh);
}

// ---------------- prep: window, bin-index, zero bins ----------------
__global__ __launch_bounds__(256) void k_prep(float *__restrict__ win,
                                              double *__restrict__ bins,
                                              uint8_t *__restrict__ bidx) {
  int t = blockIdx.x * 256 + threadIdx.x;     // 784*256 == 200704
  int a = t / IMGN, b = t % IMGN;
  double yy = (double)((a + 224) % IMGN) - 223.5;
  double xx = (double)((b + 224) % IMGN) - 223.5;
  double r2 = xx * xx + yy * yy;
  uint8_t idx = 255;
  if (r2 >= 249.76125 && r2 <= 90163.81125) {
    double th = atan2(yy, xx);
    if (th < 0.0) th += 6.283185307179586476925286766559;
    int i = (int)(th / 0.17453292519943295769236907684886);
    if (i > 35) i = 35;
    if (i < 0) i = 0;
    idx = (uint8_t)i;
  }
  bidx[t] = idx;
  if (t < IMGN) {
    double ang = 6.283185307179586476925286766559 * (double)t / 448.0;
    win[t] = (float)(0.5 - 0.5 * cos(ang));
  }
  if (t < NBATCH * NBINS) bins[t] = 0.0;
}

// ---------------- twiddle frag matrices (6) ----------------
__global__ __launch_bounds__(256) void k_tw(short8 *__restrict__ tch, short8 *__restrict__ tcl,
                                            short8 *__restrict__ tsh, short8 *__restrict__ tsl,
                                            short8 *__restrict__ ntsh, short8 *__restrict__ ntsl) {
  int wid = blockIdx.x * 256 + threadIdx.x;   // 98*256 = 25088 = 28*14*64
  int lane = wid & 63;
  int tmp = wid >> 6;
  int kb = tmp % 14, mb = tmp / 14;
  int m = mb * 16 + (lane & 15);
  int k0 = kb * 32 + (lane >> 4) * 8;
  short8 ch, cl, sh, sl, nh, nl;
#pragma unroll
  for (int e = 0; e < 8; ++e) {
    int mm = (m * (k0 + e)) % IMGN;
    double ang = -6.283185307179586476925286766559 * (double)mm / 448.0;
    float c = (float)cos(ang), s = (float)sin(ang);
    unsigned short h, l;
    split2(c, h, l); ch[e] = (short)h; cl[e] = (short)l;
    split2(s, h, l); sh[e] = (short)h; sl[e] = (short)l;
    nh[e] = (short)(h ^ 0x8000u); nl[e] = (short)(l ^ 0x8000u);  // exact -s split
  }
  tch[wid] = ch; tcl[wid] = cl; tsh[wid] = sh; tsl[wid] = sl; ntsh[wid] = nh; ntsl[wid] = nl;
}

// ---------------- weight frag matrices (B-operand layout) ----------------
__global__ __launch_bounds__(256) void k_wconv(const float *__restrict__ w1, const float *__restrict__ w2,
                                               short8 *__restrict__ w1h, short8 *__restrict__ w1l,
                                               short8 *__restrict__ w2h, short8 *__restrict__ w2l) {
  int wid = blockIdx.x * 256 + threadIdx.x;   // 288*256 = 73728 = 48*24*64
  const float *src = blockIdx.y ? w2 : w1;
  short8 *dh = blockIdx.y ? w2h : w1h;
  short8 *dl = blockIdx.y ? w2l : w1l;
  int lane = wid & 63;
  int tmp = wid >> 6;
  int kb = tmp % 24, nb = tmp / 24;
  int n = nb * 16 + (lane & 15);
  int k0 = kb * 32 + (lane >> 4) * 8;
  const float *p = src + (size_t)n * 768 + k0;
  short8 vh, vl;
#pragma unroll
  for (int e = 0; e < 8; ++e) {
    unsigned short h, l;
    split2(p[e], h, l);
    vh[e] = (short)h; vl[e] = (short)l;
  }
  dh[wid] = vh; dl[wid] = vl;
}

// ---------------- windowed grayscale frag matrices (rows B) ----------------
__global__ __launch_bounds__(256) void k_gprep(const float *__restrict__ img, const float *__restrict__ win,
                                               short8 *__restrict__ gh, short8 *__restrict__ gl) {
  int wid = blockIdx.x * 256 + threadIdx.x;   // 6272*256 = 1605632 = 1792*14*64
  int lane = wid & 63;
  int tmp = wid >> 6;
  int kb = tmp % 14, nb = tmp / 14;
  int n = nb * 16 + (lane & 15);              // n = b*448 + y
  int b = n / 448, y = n % 448;
  int x0 = kb * 32 + (lane >> 4) * 8;
  const float *p = img + (size_t)b * 3 * HW + y * IMGN + x0;
  float wy = win[y];
  short8 vh, vl;
#pragma unroll
  for (int e = 0; e < 8; ++e) {
    float r = p[e], g = p[HW + e], bl = p[2 * HW + e];
    float t0 = (r * 0.229f + 0.485f) * 0.2989f;
    float t1 = (g * 0.224f + 0.456f) * 0.587f;
    float t2 = (bl * 0.225f + 0.406f) * 0.114f;
    float v = ((t0 + t1) + t2) * wy * win[x0 + e];
    unsigned short h, l;
    split2(v, h, l);
    vh[e] = (short)h; vl[e] = (short)l;
  }
  gh[wid] = vh; gl[wid] = vl;
}

// ---------------- rows GEMM: C1[v,(b,y)] = sum_x T[v,x]*G[x,(b,y)] ----------------
__global__ __launch_bounds__(256) void k_rows(const short8 *__restrict__ tch, const short8 *__restrict__ tcl,
                                              const short8 *__restrict__ tsh, const short8 *__restrict__ tsl,
                                              const short8 *__restrict__ gh, const short8 *__restrict__ gl,
                                              float *__restrict__ cr, float *__restrict__ ci) {
  int lane = threadIdx.x & 63, w = threadIdx.x >> 6;
  int mt0 = blockIdx.x * 4;            // 4 blocks -> mtiles 0..15 (M=256)
  int nt0 = blockIdx.y * 8 + w * 2;    // 224 blocks -> ntiles 0..1791
  floatx4 ar[4][2] = {}, ai[4][2] = {};
  const short8 *APc[3] = { tch, tch, tcl };
  const short8 *APs[3] = { tsh, tsh, tsl };
  const short8 *BP[3]  = { gh,  gl,  gh  };
#pragma unroll
  for (int t = 0; t < 3; ++t) {
    const short8 *ac = APc[t], *as_ = APs[t], *bp = BP[t];
    for (int kb = 0; kb < 14; ++kb) {
      short8 a_c[4], a_s[4], b[2];
#pragma unroll
      for (int mf = 0; mf < 4; ++mf) {
        int off = ((mt0 + mf) * 14 + kb) * 64 + lane;
        a_c[mf] = ac[off]; a_s[mf] = as_[off];
      }
#pragma unroll
      for (int nf = 0; nf < 2; ++nf) b[nf] = bp[((nt0 + nf) * 14 + kb) * 64 + lane];
#pragma unroll
      for (int mf = 0; mf < 4; ++mf)
#pragma unroll
        for (int nf = 0; nf < 2; ++nf) {
          ar[mf][nf] = __builtin_amdgcn_mfma_f32_16x16x32_bf16(a_c[mf], b[nf], ar[mf][nf], 0, 0, 0);
          ai[mf][nf] = __builtin_amdgcn_mfma_f32_16x16x32_bf16(a_s[mf], b[nf], ai[mf][nf], 0, 0, 0);
        }
    }
  }
  int g = lane >> 4, c = lane & 15;
#pragma unroll
  for (int mf = 0; mf < 4; ++mf)
#pragma unroll
    for (int nf = 0; nf < 2; ++nf) {
      int n = (nt0 + nf) * 16 + c;
#pragma unroll
      for (int r = 0; r < 4; ++r) {
        int v = (mt0 + mf) * 16 + 4 * g + r;
        cr[(size_t)v * 28672 + n] = ar[mf][nf][r];
        ci[(size_t)v * 28672 + n] = ai[mf][nf][r];
      }
    }
}

// ---------------- repack C1 fp32 -> cols B frag mats (n = b*240+v, k = y) ----------------
__global__ __launch_bounds__(256) void k_repack(const float *__restrict__ cr, const float *__restrict__ ci,
                                                short8 *__restrict__ crh, short8 *__restrict__ crl,
                                                short8 *__restrict__ cih, short8 *__restrict__ cil) {
  int wid = blockIdx.x * 256 + threadIdx.x;   // 3360*256 = 860160 = 960*14*64
  int lane = wid & 63;
  int tmp = wid >> 6;
  int kb = tmp % 14, nb = tmp / 14;
  int n = nb * 16 + (lane & 15);              // n = b*240 + v
  int b = n / 240, v = n % 240;
  int y0 = kb * 32 + (lane >> 4) * 8;
  const float *pr = cr + (size_t)v * 28672 + b * 448 + y0;
  const float *pi = ci + (size_t)v * 28672 + b * 448 + y0;
  short8 rh, rl, ih, il;
#pragma unroll
  for (int e = 0; e < 8; ++e) {
    unsigned short h, l;
    split2(pr[e], h, l); rh[e] = (short)h; rl[e] = (short)l;
    split2(pi[e], h, l); ih[e] = (short)h; il[e] = (short)l;
  }
  crh[wid] = rh; crl[wid] = rl; cih[wid] = ih; cil[wid] = il;
}

// ---------------- cols GEMM + power + binning ----------------
__global__ __launch_bounds__(256) void k_cols(const short8 *__restrict__ tch, const short8 *__restrict__ tcl,
                                              const short8 *__restrict__ tsh, const short8 *__restrict__ tsl,
                                              const short8 *__restrict__ ntsh, const short8 *__restrict__ ntsl,
                                              const short8 *__restrict__ crh, const short8 *__restrict__ crl,
                                              const short8 *__restrict__ cih, const short8 *__restrict__ cil,
                                              const uint8_t *__restrict__ bidx, double *__restrict__ bins) {
  __shared__ double lb[72];                  // 2 possible b values per block
  int tid = threadIdx.x;
  if (tid < 72) lb[tid] = 0.0;
  __syncthreads();
  int lane = tid & 63, w = tid >> 6;
  int mt0 = blockIdx.x * 4;                  // 7 blocks -> mtiles 0..27 (M=448)
  int nt0 = blockIdx.y * 8 + w * 2;          // 120 blocks -> ntiles 0..959 (N=15360)
  int base_b = (blockIdx.y * 128) / 240;
  floatx4 fr[4][2] = {}, fi[4][2] = {};
  const short8 *AR[6] = { tch, tch, tcl, ntsh, ntsh, ntsl };
  const short8 *AI[6] = { tsh, tsh, tsl, tch,  tch,  tcl  };
  const short8 *BB[6] = { crh, crl, crh, cih,  cil,  cih  };
#pragma unroll
  for (int t = 0; t < 6; ++t) {
    const short8 *arp = AR[t], *aip = AI[t], *bp = BB[t];
    for (int kb = 0; kb < 14; ++kb) {
      short8 a_r[4], a_i[4], b[2];
#pragma unroll
      for (int mf = 0; mf < 4; ++mf) {
        int off = ((mt0 + mf) * 14 + kb) * 64 + lane;
        a_r[mf] = arp[off]; a_i[mf] = aip[off];
      }
#pragma unroll
      for (int nf = 0; nf < 2; ++nf) b[nf] = bp[((nt0 + nf) * 14 + kb) * 64 + lane];
#pragma unroll
      for (int mf = 0; mf < 4; ++mf)
#pragma unroll
        for (int nf = 0; nf < 2; ++nf) {
          fr[mf][nf] = __builtin_amdgcn_mfma_f32_16x16x32_bf16(a_r[mf], b[nf], fr[mf][nf], 0, 0, 0);
          fi[mf][nf] = __builtin_amdgcn_mfma_f32_16x16x32_bf16(a_i[mf], b[nf], fi[mf][nf], 0, 0, 0);
        }
    }
  }
  int g = lane >> 4, c = lane & 15;
#pragma unroll
  for (int mf = 0; mf < 4; ++mf)
#pragma unroll
    for (int nf = 0; nf < 2; ++nf) {
      int n = (nt0 + nf) * 16 + c;           // n = b*240 + v
      int v = n % 240;
      int bloc = n / 240 - base_b;
#pragma unroll
      for (int r = 0; r < 4; ++r) {
        int u = (mt0 + mf) * 16 + 4 * g + r;
        if (v < 225) {
          float frv = fr[mf][nf][r], fiv = fi[mf][nf][r];
          double P = (double)frv * frv + (double)fiv * fiv;
          int i1 = bidx[u * IMGN + v];
          if (i1 < 36) atomicAdd(&lb[bloc * 36 + i1], P);
          if (v >= 1 && v <= 223) {
            int i2 = bidx[((IMGN - u) % IMGN) * IMGN + (IMGN - v)];
            if (i2 < 36) atomicAdd(&lb[bloc * 36 + i2], P);
          }
        }
      }
    }
  __syncthreads();
  if (tid < 72) {
    int bb = base_b + tid / 36;
    if (bb < NBATCH && lb[tid] != 0.0) atomicAdd(&bins[bb * NBINS + (tid % 36)], lb[tid]);
  }
}

// ---------------- entropy -> ape -> drop prob ----------------
__global__ void k_probs(const double *__restrict__ bins, float *__restrict__ ts) {
  int b = threadIdx.x;
  if (b >= NBATCH) return;
  double T = 0.0;
  for (int i = 0; i < NBINS; ++i) T += bins[b * NBINS + i];
  double H = 0.0;
  for (int i = 0; i < NBINS; ++i) {
    double p = bins[b * NBINS + i] / (T + 1e-12);
    H -= p * log(p + 1e-12);
  }
  double ape = H / 3.5835189384561099;
  if (ape > 1.0) ape = 1.0;
  if (ape < 0.0) ape = 0.0;
  if (T <= 1e-12) ape = 0.0;
  double adj = tanh((0.78 - ape) * 4.0);
  double drop = (adj >= 0.0) ? (0.3 + adj * 0.3) : (0.3 + adj * 0.2);
  if (drop < 0.1) drop = 0.1;
  if (drop > 0.6) drop = 0.6;
  float p32 = (float)drop;
  ts[b] = 1.0f - p32;
  ts[NBATCH + b] = 1.0f / (1.0f - p32 + 1e-8f);
}

// ---------------- dropout(x) -> A-frag split mats ----------------
__global__ __launch_bounds__(256) void k_dropfrag(const float *__restrict__ x, const float *__restrict__ ts,
                                                  short8 *__restrict__ xh, short8 *__restrict__ xl,
                                                  uint32_t k0, uint32_t k1) {
  int wid = blockIdx.x * 256 + threadIdx.x;   // 6144*256 = 1572864 = 1024*24*64
  int lane = wid & 63;
  int tmp = wid >> 6;
  int kb = tmp % 24, mb = tmp / 24;
  int m = mb * 16 + (lane & 15);              // token
  int d0 = kb * 32 + (lane >> 4) * 8;
  int bi = m >> 8;
  float t = ts[bi], s = ts[NBATCH + bi];
  const float *p = x + (size_t)m * 768 + d0;
  short8 vh, vl;
#pragma unroll
  for (int e = 0; e < 8; ++e) {
    uint32_t idx = (uint32_t)m * 768u + (uint32_t)(d0 + e);
    float u = tf_uniform(k0, k1, idx);
    float v = (u < t) ? p[e] * s : 0.0f;
    unsigned short h, l;
    split2(v, h, l);
    vh[e] = (short)h; vl[e] = (short)l;
  }
  xh[wid] = vh; xl[wid] = vl;
}

// ---------------- MLP GEMM: M=16384 tokens, N=768, K=768 ----------------
// MODE 1: gelu+dropout, write h frag mats.  MODE 2: dropout, write y fp32.
template <int MODE>
__global__ __launch_bounds__(256) void k_mlp(const short8 *__restrict__ ah, const short8 *__restrict__ al,
                                             const short8 *__restrict__ bh, const short8 *__restrict__ bl,
                                             const float *__restrict__ ts, float *__restrict__ out,
                                             short8 *__restrict__ oh, short8 *__restrict__ ol,
                                             uint32_t k0, uint32_t k1) {
  int lane = threadIdx.x & 63, w = threadIdx.x >> 6;
  int mt0 = blockIdx.x * 4;            // 256 blocks -> mtiles 0..1023
  int nt0 = blockIdx.y * 8 + w * 2;    // 6 blocks  -> ntiles 0..47
  floatx4 acc[4][2] = {};
  const short8 *AP[3] = { ah, ah, al };
  const short8 *BP[3] = { bh, bl, bh };
#pragma unroll
  for (int t = 0; t < 3; ++t) {
    const short8 *ap = AP[t], *bp = BP[t];
    for (int kb = 0; kb < 24; ++kb) {
      short8 a[4], b[2];
#pragma unroll
      for (int mf = 0; mf < 4; ++mf) a[mf] = ap[((mt0 + mf) * 24 + kb) * 64 + lane];
#pragma unroll
      for (int nf = 0; nf < 2; ++nf) b[nf] = bp[((nt0 + nf) * 24 + kb) * 64 + lane];
#pragma unroll
      for (int mf = 0; mf < 4; ++mf)
#pragma unroll
        for (int nf = 0; nf < 2; ++nf)
          acc[mf][nf] = __builtin_amdgcn_mfma_f32_16x16x32_bf16(a[mf], b[nf], acc[mf][nf], 0, 0, 0);
    }
  }
  int g = lane >> 4, c = lane & 15;
#pragma unroll
  for (int mf = 0; mf < 4; ++mf)
#pragma unroll
    for (int nf = 0; nf < 2; ++nf) {
      int n = (nt0 + nf) * 16 + c;
#pragma unroll
      for (int r = 0; r < 4; ++r) {
        int m = (mt0 + mf) * 16 + 4 * g + r;
        float val = acc[mf][nf][r];
        if (MODE == 1)
          val = 0.5f * val * (1.0f + erff(val * 0.70710678118654752440f));
        int bi = m >> 8;
        float t = ts[bi], s = ts[NBATCH + bi];
        uint32_t idx = (uint32_t)m * 768u + (uint32_t)n;
        float u = tf_uniform(k0, k1, idx);
        val = (u < t) ? val * s : 0.0f;
        if (MODE == 1) {
          unsigned short hh, hl;
          split2(val, hh, hl);
          int kb2 = n >> 5;
          int lane2 = (m & 15) + 16 * ((n & 31) >> 3);
          int e2 = n & 7;
          size_t word = ((size_t)(m >> 4) * 24 + kb2) * 64 + lane2;
          ((unsigned short *)oh)[word * 8 + e2] = hh;
          ((unsigned short *)ol)[word * 8 + e2] = hl;
        } else {
          out[(size_t)m * 768 + n] = val;
        }
      }
    }
}

// ---------------- launch ----------------
extern "C" void kernel_launch(void *const *d_in, const int *in_sizes, int n_in,
                              void *d_out, int out_size, void *d_ws, size_t ws_size,
                              hipStream_t stream) {
  (void)in_sizes; (void)n_in; (void)out_size; (void)ws_size;
  const float *images = (const float *)d_in[0];
  const float *x  = (const float *)d_in[1];
  const float *w1 = (const float *)d_in[2];
  const float *w2 = (const float *)d_in[3];

  char *ws = (char *)d_ws;
  float   *win  = (float *)  (ws + WS_WIN);
  double  *bins = (double *) (ws + WS_BINS);
  float   *ts   = (float *)  (ws + WS_TS);
  uint8_t *bidx = (uint8_t *)(ws + WS_BIDX);
  short8  *tch  = (short8 *) (ws + WS_TW + 0 * TWSZ);
  short8  *tcl  = (short8 *) (ws + WS_TW + 1 * TWSZ);
  short8  *tsh  = (short8 *) (ws + WS_TW + 2 * TWSZ);
  short8  *tsl  = (short8 *) (ws + WS_TW + 3 * TWSZ);
  short8  *ntsh = (short8 *) (ws + WS_TW + 4 * TWSZ);
  short8  *ntsl = (short8 *) (ws + WS_TW + 5 * TWSZ);
  short8  *w1h  = (short8 *) (ws + WS_W + 0 * WSZ);
  short8  *w1l  = (short8 *) (ws + WS_W + 1 * WSZ);
  short8  *w2h  = (short8 *) (ws + WS_W + 2 * WSZ);
  short8  *w2l  = (short8 *) (ws + WS_W + 3 * WSZ);
  // REG1: G -> colsB -> xd
  short8  *gh   = (short8 *) (ws + WS_REG1 + 0 * GSZ);
  short8  *gl   = (short8 *) (ws + WS_REG1 + 1 * GSZ);
  short8  *crh  = (short8 *) (ws + WS_REG1 + 0 * CBSZ);
  short8  *crl  = (short8 *) (ws + WS_REG1 + 1 * CBSZ);
  short8  *cih  = (short8 *) (ws + WS_REG1 + 2 * CBSZ);
  short8  *cil  = (short8 *) (ws + WS_REG1 + 3 * CBSZ);
  short8  *xh   = (short8 *) (ws + WS_REG1 + 0 * XSZ);
  short8  *xl   = (short8 *) (ws + WS_REG1 + 1 * XSZ);
  // REG2: Cr/Ci -> h
  float   *cr   = (float *)  (ws + WS_REG2 + 0 * CRSZ);
  float   *ci   = (float *)  (ws + WS_REG2 + 1 * CRSZ);
  short8  *hh_  = (short8 *) (ws + WS_REG2 + 0 * XSZ);
  short8  *hl_  = (short8 *) (ws + WS_REG2 + 1 * XSZ);
  float   *yout = (float *)d_out;

  uint32_t keys[6];
  tf2x32(0u, 1u, 0u, 0u, keys[0], keys[1]);
  tf2x32(0u, 1u, 0u, 1u, keys[2], keys[3]);
  tf2x32(0u, 1u, 0u, 2u, keys[4], keys[5]);

  k_prep<<<784, 256, 0, stream>>>(win, bins, bidx);
  k_tw<<<98, 256, 0, stream>>>(tch, tcl, tsh, tsl, ntsh, ntsl);
  k_wconv<<<dim3(288, 2), 256, 0, stream>>>(w1, w2, w1h, w1l, w2h, w2l);
  k_gprep<<<6272, 256, 0, stream>>>(images, win, gh, gl);
  k_rows<<<dim3(4, 224), 256, 0, stream>>>(tch, tcl, tsh, tsl, gh, gl, cr, ci);
  k_repack<<<3360, 256, 0, stream>>>(cr, ci, crh, crl, cih, cil);
  k_cols<<<dim3(7, 120), 256, 0, stream>>>(tch, tcl, tsh, tsl, ntsh, ntsl,
                                           crh, crl, cih, cil, bidx, bins);
  k_probs<<<1, 64, 0, stream>>>(bins, ts);
  k_dropfrag<<<6144, 256, 0, stream>>>(x, ts, xh, xl, keys[0], keys[1]);
  k_mlp<1><<<dim3(256, 6), 256, 0, stream>>>(xh, xl, w1h, w1l, ts, yout, hh_, hl_, keys[2], keys[3]);
  k_mlp<2><<<dim3(256, 6), 256, 0, stream>>>(hh_, hl_, w2h, w2l, ts, yout, hh_, hl_, keys[4], keys[5]);
}